// Round 9
// baseline (190.561 us; speedup 1.0000x reference)
//
#include <hip/hip_runtime.h>
#include <hip/hip_bf16.h>

#define N_PTS 16384
#define PER   2048
#define M_CTR 4096
#define KNB   64
#define C_IN  128
#define HID   256
#define C_OUT 256

typedef unsigned short u16;
typedef unsigned int u32;
typedef __attribute__((ext_vector_type(8))) short s8v;    // 8 bf16 (4 VGPRs)
typedef __attribute__((ext_vector_type(4))) float f4v;
typedef __attribute__((ext_vector_type(4))) unsigned int u4v;

static __device__ __forceinline__ u16 f2bf(float f) {
    union { float f; unsigned int i; } v; v.f = f;
    unsigned int r = v.i + 0x7FFFu + ((v.i >> 16) & 1u);
    return (u16)(r >> 16);
}

// ---------------------------------------------------------------- fused pre-pass
// r8: ballq (blocks 0..4095, r2-exact logic) + gemm_xw (blocks 4096..4415) in ONE
// kernel. The W1aT/W1bT intermediate is GONE: gemm-mode builds B fragments directly
// from W1 with the same f2bf -> bit-identical bf16 -> bit-identical MFMA results.
// gemm-mode re-tiled to two 32-row groups (acc[2][4]) to keep fused VGPR ~70 so
// ballq blocks keep high occupancy. Removes one kernel launch; gemm blocks overlap
// ballq's tail. ballq math/compaction/tail byte-equal to the proven r2 version.
__global__ __launch_bounds__(256) void pre_kernel(
        const float* __restrict__ pos, const float* __restrict__ x,
        const float* __restrict__ W1, const float* __restrict__ W2,
        const float* __restrict__ b1,
        int* __restrict__ nbr, int* __restrict__ cnt,
        u16* __restrict__ W2T, u16* __restrict__ u_out, float* __restrict__ v_out) {
    __shared__ __align__(16) char sh[64 * 136 * 2];      // union: ballq 8196 B | gemm x_lds 17408 B
    int blk = blockIdx.x, tid = threadIdx.x;

    if (blk < 4096) {
        // ================= ballq mode (r2-exact; W2T prep kept, W1aT/W1bT prep dropped)
        float* cd2  = (float*)sh;                        // [1024]
        int*   cidx = (int*)(sh + 4096);                 // [1024]
        int*   s_np = (int*)(sh + 8192);
        int m = blk;

        if (m < 256) {
            int gid = m * 256 + tid;
            int cc = gid >> 8, k = gid & 255;
            W2T[gid] = f2bf(W2[k * 256 + cc]);           // W2T[c][k]
        }

        int c = m * 4;
        int base = (m >> 9) << 11;                        // cloud start
        int ln = tid & 63;
        if (tid == 0) *s_np = 0;
        __syncthreads();
        float cx = pos[c * 3 + 0], cy = pos[c * 3 + 1], cz = pos[c * 3 + 2];
        float A = __fadd_rn(__fadd_rn(__fmul_rn(cx, cx), __fmul_rn(cy, cy)), __fmul_rn(cz, cz));
        float c2x = __fmul_rn(2.0f, cx);
        float c2y = __fmul_rn(2.0f, cy);
        float c2z = __fmul_rn(2.0f, cz);
        for (int s = 0; s < 8; ++s) {
            int j = base + tid + (s << 8);
            float px = pos[j * 3 + 0], py = pos[j * 3 + 1], pz = pos[j * 3 + 2];
            float B = __fadd_rn(__fadd_rn(__fmul_rn(px, px), __fmul_rn(py, py)), __fmul_rn(pz, pz));
            float C = __fmaf_rn(c2z, pz, __fmaf_rn(c2y, py, __fmul_rn(c2x, px)));
            float d2 = __fsub_rn(__fadd_rn(A, B), C);
            bool hit = (d2 <= 0.0625f);
            unsigned long long mk = __ballot(hit);
            int nb = __popcll(mk & ((1ull << ln) - 1ull));
            int tot = __popcll(mk);
            int bidx = 0;
            if (ln == 0 && tot) bidx = atomicAdd(s_np, tot);
            bidx = __shfl(bidx, 0, 64);
            if (hit) {
                int a = bidx + nb;
                if (a < 1024) { cd2[a] = d2; cidx[a] = j; }
            }
        }
        __syncthreads();
        int V = *s_np < 1024 ? *s_np : 1024;
        if (V <= KNB) {
            if (tid < KNB) nbr[m * KNB + tid] = (tid < V) ? cidx[tid] : c;
            if (tid == 0) cnt[m] = V;
        } else {
            for (int e = tid; e < V; e += 256) {
                float de = cd2[e]; int ie = cidx[e];
                int rank = 0;
                for (int q = 0; q < V; ++q) {
                    float dq = cd2[q];
                    rank += (dq < de) || (dq == de && cidx[q] < ie);
                }
                if (rank < KNB) nbr[m * KNB + rank] = cidx[e];
            }
            if (tid == 0) cnt[m] = KNB;
        }
    } else {
        // ================= gemm mode: u = x@W1a (bb<256) / v = x[4m]@W1b + b1 (bb>=256)
        u16* x_lds = (u16*)sh;                           // [64][136]
        int bb = blk - 4096;
        int mode = bb >= 256 ? 1 : 0;
        if (mode) bb -= 256;
        {
            int r = tid >> 2, q = tid & 3;
            int xrow = bb * 64 + r;
            if (mode) xrow *= 4;
            const float* xp = x + xrow * C_IN + q * 32;
            u16* dst = x_lds + r * 136 + q * 32;
            for (int i = 0; i < 8; ++i) {
                f4v f = *(const f4v*)(xp + i * 4);
                dst[i * 4 + 0] = f2bf(f[0]);
                dst[i * 4 + 1] = f2bf(f[1]);
                dst[i * 4 + 2] = f2bf(f[2]);
                dst[i * 4 + 3] = f2bf(f[3]);
            }
        }
        __syncthreads();
        int lane = tid & 63, w = tid >> 6;
        int quad = lane >> 4, l16 = lane & 15;
        int cb = w * 64;
        for (int g = 0; g < 2; ++g) {                    // two 32-row groups: acc[2][4]
            f4v acc[2][4] = {};
            for (int k0 = 0; k0 < 128; k0 += 32) {
                s8v a[2], b[4];
                for (int rt = 0; rt < 2; ++rt)
                    a[rt] = *(const s8v*)&x_lds[((g * 2 + rt) * 16 + l16) * 136 + k0 + quad * 8];
                for (int ct = 0; ct < 4; ++ct) {
                    // B fragment straight from W1 (row k, col n): same f2bf => bit-identical
                    const float* wp = W1 + ((mode ? 128 : 0) + k0 + quad * 8) * 256 + cb + ct * 16 + l16;
                    u4v wv;
                    #pragma unroll
                    for (int d = 0; d < 4; ++d)
                        wv[d] = (u32)f2bf(wp[(2 * d) * 256]) | ((u32)f2bf(wp[(2 * d + 1) * 256]) << 16);
                    b[ct] = *(s8v*)&wv;
                }
                for (int rt = 0; rt < 2; ++rt)
                    for (int ct = 0; ct < 4; ++ct)
                        acc[rt][ct] = __builtin_amdgcn_mfma_f32_16x16x32_bf16(a[rt], b[ct], acc[rt][ct], 0, 0, 0);
            }
            for (int rt = 0; rt < 2; ++rt)
                for (int ct = 0; ct < 4; ++ct)
                    for (int gg = 0; gg < 4; ++gg) {
                        int row = (g * 2 + rt) * 16 + quad * 4 + gg;
                        int col = cb + ct * 16 + l16;
                        float val = acc[rt][ct][gg];
                        int orow = bb * 64 + row;
                        if (mode == 0) u_out[orow * 256 + col] = f2bf(val);
                        else           v_out[orow * 256 + col] = val + b1[col];
                    }
        }
    }
}

// ---------------------------------------------------------------- fused edge conv
// BYTE-EXACT r2 structure (proven 57.8-58.7us across r3/r8: 8 centers/block, grid
// 512, w1c in LDS, bs loaded AFTER the barrier, NO setprio).
// HARD RULES (6x confirmed, r1/r4/r5/r6/r7): allocator pins 64 VGPRs here;
//  - any extra live state (cross-barrier or intra-phase-1) spills -> FETCH/WRITE
//    explode by 30-90 MB;
//  - even side-effect scalar intrinsics (s_setprio) perturb scheduling into spill.
// This schedule is the envelope's fixed point: DO NOT TOUCH.
__global__ __launch_bounds__(512, 4) void edge_kernel(
        const u16* __restrict__ u, const float* __restrict__ v,
        const u16* __restrict__ W2T, const float* __restrict__ W1,
        const float* __restrict__ b2, const float* __restrict__ pos,
        const float* __restrict__ lframes, const int* __restrict__ batch,
        const int* __restrict__ nbrg, const int* __restrict__ cnt,
        float* __restrict__ out0, float* __restrict__ out_pos,
        float* __restrict__ out_batch, float* __restrict__ out_lf) {
    __shared__ u16   h_lds[64 * 264];                    // 33792 B
    __shared__ float w1c_lds[768];                       // 3072 B
    __shared__ f4v   relc_lds[8][64];                    // 8192 B
    __shared__ u16   nbr_lds[8][64];                     // 1024 B
    // total 46080 B; occupancy grid-capped at 2 blocks/CU

    int blk = blockIdx.x, tid = threadIdx.x;
    int m0 = ((blk & 7) << 9) | ((blk >> 3) << 3);       // 8 consecutive centers, cloud == XCD

    int lane = tid & 63, w = tid >> 6;
    int quad = lane >> 4, l16 = lane & 15;
    int cb = w * 32;                                     // 8 waves x 32 cols = 256

    // ---- pinned B: k-slices 0..3 (32 VGPRs)
    s8v bfrag[4][2];
    #pragma unroll
    for (int k0 = 0; k0 < 4; ++k0)
        #pragma unroll
        for (int ct = 0; ct < 2; ++ct)
            bfrag[k0][ct] = *(const s8v*)(W2T + (cb + ct * 16 + l16) * 256 + k0 * 32 + quad * 8);

    // ---- prologue: w1c + meta for ALL 8 centers (exactly one (center,t) per thread)
    for (int i = tid; i < 768; i += 512) w1c_lds[i] = W1[65536 + i];
    {
        int pr = tid >> 6, t = tid & 63;
        int mm = m0 + pr, cc = mm * 4;
        int j = nbrg[mm * KNB + t];
        nbr_lds[pr][t] = (u16)j;
        float rx = pos[j * 3 + 0] - pos[cc * 3 + 0];
        float ry = pos[j * 3 + 1] - pos[cc * 3 + 1];
        float rz = pos[j * 3 + 2] - pos[cc * 3 + 2];
        const float* lf = lframes + cc * 9;
        f4v r;
        r[0] = lf[0] * rx + lf[1] * ry + lf[2] * rz;
        r[1] = lf[3] * rx + lf[4] * ry + lf[5] * rz;
        r[2] = lf[6] * rx + lf[7] * ry + lf[8] * rz;
        r[3] = 0.0f;
        relc_lds[pr][t] = r;
    }
    if (tid >= 256 && tid < 384) {                       // aux outputs, all 8 centers
        int g = (tid - 256) >> 4, t = tid & 15;
        int mm = m0 + g, cc = mm * 4;
        if (t < 3)            out_pos[mm * 3 + t] = pos[cc * 3 + t];
        else if (t == 3)      out_batch[mm] = (float)batch[cc];
        else if (t < 13)      out_lf[mm * 9 + (t - 4)] = lframes[cc * 9 + (t - 4)];
    }

    int co = (tid & 31) * 8;
    int rs = tid >> 5;                                   // 0..15
    __syncthreads();                                     // meta + w1c ready

    for (int p = 0; p < 8; ++p) {
        int cvp = cnt[m0 + p];                           // uniform, L2-hot
        // ---- phase 1: h[64][256] = relu(u[nbr] + v + relc @ W1c)
        {
            const float* vp = v + (m0 + p) * 256 + co;
            f4v vq0 = *(const f4v*)vp;
            f4v vq1 = *(const f4v*)(vp + 4);
            f4v wa0 = *(const f4v*)&w1c_lds[co],       wa1 = *(const f4v*)&w1c_lds[co + 4];
            f4v wb0 = *(const f4v*)&w1c_lds[256 + co], wb1 = *(const f4v*)&w1c_lds[256 + co + 4];
            f4v wc0 = *(const f4v*)&w1c_lds[512 + co], wc1 = *(const f4v*)&w1c_lds[512 + co + 4];
            u4v uu[4];
            f4v rr[4];
            #pragma unroll
            for (int i2 = 0; i2 < 4; ++i2) {             // issue all 4 gathers first
                int rl = rs + i2 * 16;
                int j = (int)nbr_lds[p][rl];
                uu[i2] = *(const u4v*)(u + j * 256 + co);
                rr[i2] = relc_lds[p][rl];
            }
            #pragma unroll
            for (int i2 = 0; i2 < 4; ++i2) {
                int rl = rs + i2 * 16;
                f4v r = rr[i2];
                float p8[8];
                #pragma unroll
                for (int e = 0; e < 8; ++e) {
                    u32 bits = (e & 1) ? (uu[i2][e >> 1] & 0xFFFF0000u) : (uu[i2][e >> 1] << 16);
                    float va = (e < 4) ? vq0[e] : vq1[e - 4];
                    float a0 = (e < 4) ? wa0[e] : wa1[e - 4];
                    float b0 = (e < 4) ? wb0[e] : wb1[e - 4];
                    float c0 = (e < 4) ? wc0[e] : wc1[e - 4];
                    float pre = fmaf(r[0], a0, fmaf(r[1], b0, fmaf(r[2], c0,
                                  va + __uint_as_float(bits))));
                    p8[e] = fmaxf(pre, 0.0f);
                }
                u4v pk;
                #pragma unroll
                for (int d = 0; d < 4; ++d)
                    pk[d] = __builtin_amdgcn_perm(__float_as_uint(p8[2 * d + 1]),
                                                  __float_as_uint(p8[2 * d]), 0x07060302u);
                *(u4v*)&h_lds[rl * 264 + co] = pk;
            }
        }
        __syncthreads();                                 // h ready

        // ---- phase 2: [64x256] @ [256x256(cols 32/wave)]; B: 4 pinned + 4 streamed
        s8v bs[4][2];
        #pragma unroll
        for (int kk = 0; kk < 4; ++kk)                   // issue streams early, MFMA covers
            #pragma unroll
            for (int ct = 0; ct < 2; ++ct)
                bs[kk][ct] = *(const s8v*)(W2T + (cb + ct * 16 + l16) * 256 + (4 + kk) * 32 + quad * 8);
        f4v acc[4][2] = {};
        #pragma unroll
        for (int k0 = 0; k0 < 4; ++k0) {
            s8v a[4];
            #pragma unroll
            for (int rt = 0; rt < 4; ++rt)
                a[rt] = *(const s8v*)&h_lds[(rt * 16 + l16) * 264 + k0 * 32 + quad * 8];
            #pragma unroll
            for (int rt = 0; rt < 4; ++rt)
                #pragma unroll
                for (int ct = 0; ct < 2; ++ct)
                    acc[rt][ct] = __builtin_amdgcn_mfma_f32_16x16x32_bf16(a[rt], bfrag[k0][ct], acc[rt][ct], 0, 0, 0);
        }
        #pragma unroll
        for (int kk = 0; kk < 4; ++kk) {
            int k0 = 4 + kk;
            s8v a[4];
            #pragma unroll
            for (int rt = 0; rt < 4; ++rt)
                a[rt] = *(const s8v*)&h_lds[(rt * 16 + l16) * 264 + k0 * 32 + quad * 8];
            #pragma unroll
            for (int rt = 0; rt < 4; ++rt)
                #pragma unroll
                for (int ct = 0; ct < 2; ++ct)
                    acc[rt][ct] = __builtin_amdgcn_mfma_f32_16x16x32_bf16(a[rt], bs[kk][ct], acc[rt][ct], 0, 0, 0);
        }
        // ---- epilogue: masked max over rows, + b2
        int mout = m0 + p;
        #pragma unroll
        for (int ct = 0; ct < 2; ++ct) {
            float mx = -__builtin_inff();
            #pragma unroll
            for (int rt = 0; rt < 4; ++rt)
                #pragma unroll
                for (int g = 0; g < 4; ++g) {
                    int row = rt * 16 + quad * 4 + g;
                    float val = acc[rt][ct][g];
                    if (row < cvp) mx = fmaxf(mx, val);
                }
            mx = fmaxf(mx, __shfl_xor(mx, 16, 64));
            mx = fmaxf(mx, __shfl_xor(mx, 32, 64));
            if (lane < 16)
                out0[mout * 256 + cb + ct * 16 + l16] = mx + b2[cb + ct * 16 + l16];
        }
        if (p < 7) __syncthreads();                      // protect h before next overwrite
    }
}

extern "C" void kernel_launch(void* const* d_in, const int* in_sizes, int n_in,
                              void* d_out, int out_size, void* d_ws, size_t ws_size,
                              hipStream_t stream) {
    const float* x       = (const float*)d_in[0];
    const float* pos     = (const float*)d_in[1];
    const int*   batch   = (const int*)d_in[2];
    const float* lframes = (const float*)d_in[3];
    const float* W1      = (const float*)d_in[4];
    const float* b1      = (const float*)d_in[5];
    const float* W2      = (const float*)d_in[6];
    const float* b2      = (const float*)d_in[7];

    float* out       = (float*)d_out;
    float* out_pos   = out + M_CTR * 256;
    float* out_batch = out_pos + M_CTR * 3;
    float* out_lf    = out_batch + M_CTR;

    char* ws = (char*)d_ws;
    u16*   u_ws = (u16*)(ws);                    // N*256 bf16   = 8 MB
    float* v_ws = (float*)(ws + 8388608);        // M*256 f32    = 4 MB
    u16*   W2T  = (u16*)(ws + 12713984);
    int*   nbr  = (int*)(ws + 12845056);
    int*   cntp = (int*)(ws + 13893632);

    hipLaunchKernelGGL(pre_kernel, dim3(4416), dim3(256), 0, stream,
                       pos, x, W1, W2, b1, nbr, cntp, W2T, u_ws, v_ws);
    hipLaunchKernelGGL(edge_kernel, dim3(512), dim3(512), 0, stream,
                       u_ws, v_ws, W2T, W1, b2, pos, lframes, batch, nbr, cntp,
                       out, out_pos, out_batch, out_lf);
}

// Round 10
// 172.632 us; speedup vs baseline: 1.1039x; 1.1039x over previous
//
#include <hip/hip_runtime.h>
#include <hip/hip_bf16.h>

#define N_PTS 16384
#define PER   2048
#define M_CTR 4096
#define KNB   64
#define C_IN  128
#define HID   256
#define C_OUT 256

typedef unsigned short u16;
typedef unsigned int u32;
typedef __attribute__((ext_vector_type(8))) short s8v;    // 8 bf16 (4 VGPRs)
typedef __attribute__((ext_vector_type(4))) float f4v;
typedef __attribute__((ext_vector_type(4))) unsigned int u4v;

static __device__ __forceinline__ u16 f2bf(float f) {
    union { float f; unsigned int i; } v; v.f = f;
    unsigned int r = v.i + 0x7FFFu + ((v.i >> 16) & 1u);
    return (u16)(r >> 16);
}

// ---------------------------------------------------------------- ballq (+prep folded into first 256 blocks)
// r9: per-WAVE segmented compaction. r8's counters exposed ballq at 73us,
// latency-bound on the per-iter LDS-atomicAdd(~120cy) -> shfl(~60cy) chain.
// Each wave now keeps a REGISTER count and writes hits into its private
// 256-entry segment via ballot+popcll prefix only — no atomics, no shuffles,
// no cross-wave traffic in the hot loop; ONE barrier before the tail.
// d2 math bit-identical per (center,j); candidate SET identical; (d2,idx) rank
// semantics identical (order was already nondeterministic in r2 via the atomic
// race — downstream max-aggregation is order-invariant, proven since r0).
__global__ __launch_bounds__(256) void ballq_kernel(
        const float* __restrict__ pos, int* __restrict__ nbr, int* __restrict__ cnt,
        const float* __restrict__ W1, const float* __restrict__ W2,
        u16* __restrict__ W1aT, u16* __restrict__ W1bT, u16* __restrict__ W2T) {
    __shared__ float cd2[1024];
    __shared__ int   cidx[1024];
    __shared__ int   s_cnt[4];
    int m = blockIdx.x, tid = threadIdx.x;

    if (m < 256) {                                        // weight prep, unchanged (r3-best)
        int gid = m * 256 + tid;
        int cc = gid >> 8, k = gid & 255;
        W2T[gid] = f2bf(W2[k * 256 + cc]);               // W2T[c][k]
        if (gid < 32768) {
            int c1 = gid >> 7, k1 = gid & 127;
            W1aT[gid] = f2bf(W1[k1 * 256 + c1]);         // rows 0:128
            W1bT[gid] = f2bf(W1[(k1 + 128) * 256 + c1]); // rows 128:256
        }
    }

    int c = m * 4;
    int base = (m >> 9) << 11;                            // cloud start
    int w = tid >> 6, ln = tid & 63;
    float cx = pos[c * 3 + 0], cy = pos[c * 3 + 1], cz = pos[c * 3 + 2];
    float A = __fadd_rn(__fadd_rn(__fmul_rn(cx, cx), __fmul_rn(cy, cy)), __fmul_rn(cz, cz));
    float c2x = __fmul_rn(2.0f, cx);
    float c2y = __fmul_rn(2.0f, cy);
    float c2z = __fmul_rn(2.0f, cz);
    int n = 0;                                            // wave-local register count
    for (int s = 0; s < 8; ++s) {
        int j = base + ln + ((s * 4 + w) << 6);           // wave w's chunks: w, w+4, ... (covers 2048)
        float px = pos[j * 3 + 0], py = pos[j * 3 + 1], pz = pos[j * 3 + 2];
        float B = __fadd_rn(__fadd_rn(__fmul_rn(px, px), __fmul_rn(py, py)), __fmul_rn(pz, pz));
        float C = __fmaf_rn(c2z, pz, __fmaf_rn(c2y, py, __fmul_rn(c2x, px)));
        float d2 = __fsub_rn(__fadd_rn(A, B), C);
        bool hit = (d2 <= 0.0625f);
        unsigned long long mk = __ballot(hit);
        int nb = __popcll(mk & ((1ull << ln) - 1ull));
        if (hit) {
            int a = n + nb;
            if (a < 256) { cd2[w * 256 + a] = d2; cidx[w * 256 + a] = j; }
        }
        n += __popcll(mk);
    }
    if (n > 256) n = 256;
    if (ln == 0) s_cnt[w] = n;
    __syncthreads();
    int n0 = s_cnt[0], n1 = s_cnt[1], n2 = s_cnt[2], n3 = s_cnt[3];
    int off1 = n0, off2 = n0 + n1, off3 = n0 + n1 + n2;
    int V = off3 + n3;
    if (V <= KNB) {
        if (tid < KNB) {
            int src = c;
            if (tid < V) {
                int ws, ix;
                if (tid < off1)      { ws = 0; ix = tid; }
                else if (tid < off2) { ws = 1; ix = tid - off1; }
                else if (tid < off3) { ws = 2; ix = tid - off2; }
                else                 { ws = 3; ix = tid - off3; }
                src = cidx[ws * 256 + ix];
            }
            nbr[m * KNB + tid] = src;
        }
        if (tid == 0) cnt[m] = V;
    } else {
        for (int e = tid; e < V; e += 256) {
            int ws, ix;
            if (e < off1)      { ws = 0; ix = e; }
            else if (e < off2) { ws = 1; ix = e - off1; }
            else if (e < off3) { ws = 2; ix = e - off2; }
            else               { ws = 3; ix = e - off3; }
            int pe = ws * 256 + ix;
            float de = cd2[pe]; int ie = cidx[pe];
            int rank = 0;
            for (int q = 0; q < n0; ++q) {
                float dq = cd2[q];
                rank += (dq < de) || (dq == de && cidx[q] < ie);
            }
            for (int q = 0; q < n1; ++q) {
                float dq = cd2[256 + q];
                rank += (dq < de) || (dq == de && cidx[256 + q] < ie);
            }
            for (int q = 0; q < n2; ++q) {
                float dq = cd2[512 + q];
                rank += (dq < de) || (dq == de && cidx[512 + q] < ie);
            }
            for (int q = 0; q < n3; ++q) {
                float dq = cd2[768 + q];
                rank += (dq < de) || (dq == de && cidx[768 + q] < ie);
            }
            if (rank < KNB) nbr[m * KNB + rank] = ie;
        }
        if (tid == 0) cnt[m] = KNB;
    }
}

// ---------------------------------------------------------------- fused u = x@W1a (blocks 0..255) / v = x[4m]@W1b + b1 (blocks 256..319)
// r3-best version: reads pre-transposed W1aT/W1bT (contiguous s8v fragments).
// r8 lesson: building B straight from W1 = stride-1KB scalar loads, +~25us. Keep
// the transposed intermediate.
__global__ __launch_bounds__(256) void gemm_xw_kernel(
        const float* __restrict__ x, const u16* __restrict__ W1aT, const u16* __restrict__ W1bT,
        const float* __restrict__ b1, u16* __restrict__ u_out, float* __restrict__ v_out) {
    __shared__ u16 x_lds[64 * 136];
    int blk = blockIdx.x, tid = threadIdx.x;
    int mode = blk >= 256 ? 1 : 0;
    int bb = mode ? blk - 256 : blk;
    const u16* WT = mode ? W1bT : W1aT;
    {
        int r = tid >> 2, q = tid & 3;
        int xrow = bb * 64 + r;
        if (mode) xrow *= 4;
        const float* xp = x + xrow * C_IN + q * 32;
        u16* dst = x_lds + r * 136 + q * 32;
        for (int i = 0; i < 8; ++i) {
            f4v f = *(const f4v*)(xp + i * 4);
            dst[i * 4 + 0] = f2bf(f[0]);
            dst[i * 4 + 1] = f2bf(f[1]);
            dst[i * 4 + 2] = f2bf(f[2]);
            dst[i * 4 + 3] = f2bf(f[3]);
        }
    }
    __syncthreads();
    int lane = tid & 63, w = tid >> 6;
    int quad = lane >> 4, l16 = lane & 15;
    int cb = w * 64;
    f4v acc[4][4] = {};
    for (int k0 = 0; k0 < 128; k0 += 32) {
        s8v a[4], b[4];
        for (int rt = 0; rt < 4; ++rt)
            a[rt] = *(const s8v*)&x_lds[(rt * 16 + l16) * 136 + k0 + quad * 8];
        for (int ct = 0; ct < 4; ++ct)
            b[ct] = *(const s8v*)(WT + (cb + ct * 16 + l16) * 128 + k0 + quad * 8);
        for (int rt = 0; rt < 4; ++rt)
            for (int ct = 0; ct < 4; ++ct)
                acc[rt][ct] = __builtin_amdgcn_mfma_f32_16x16x32_bf16(a[rt], b[ct], acc[rt][ct], 0, 0, 0);
    }
    for (int rt = 0; rt < 4; ++rt)
        for (int ct = 0; ct < 4; ++ct)
            for (int g = 0; g < 4; ++g) {
                int row = rt * 16 + quad * 4 + g;
                int col = cb + ct * 16 + l16;
                float val = acc[rt][ct][g];
                int orow = bb * 64 + row;
                if (mode == 0) u_out[orow * 256 + col] = f2bf(val);
                else           v_out[orow * 256 + col] = val + b1[col];
            }
}

// ---------------------------------------------------------------- fused edge conv
// BYTE-EXACT r2 structure (proven 57.8-58.7us across r3/r8: 8 centers/block, grid
// 512, w1c in LDS, bs loaded AFTER the barrier, NO setprio).
// HARD RULES (6x confirmed, r1/r4/r5/r6): allocator pins 64 VGPRs here; any extra
// live state spills (FETCH/WRITE +30-90 MB); even s_setprio perturbs scheduling
// into spill. This schedule is the envelope's fixed point: DO NOT TOUCH.
__global__ __launch_bounds__(512, 4) void edge_kernel(
        const u16* __restrict__ u, const float* __restrict__ v,
        const u16* __restrict__ W2T, const float* __restrict__ W1,
        const float* __restrict__ b2, const float* __restrict__ pos,
        const float* __restrict__ lframes, const int* __restrict__ batch,
        const int* __restrict__ nbrg, const int* __restrict__ cnt,
        float* __restrict__ out0, float* __restrict__ out_pos,
        float* __restrict__ out_batch, float* __restrict__ out_lf) {
    __shared__ u16   h_lds[64 * 264];                    // 33792 B
    __shared__ float w1c_lds[768];                       // 3072 B
    __shared__ f4v   relc_lds[8][64];                    // 8192 B
    __shared__ u16   nbr_lds[8][64];                     // 1024 B
    // total 46080 B; occupancy grid-capped at 2 blocks/CU

    int blk = blockIdx.x, tid = threadIdx.x;
    int m0 = ((blk & 7) << 9) | ((blk >> 3) << 3);       // 8 consecutive centers, cloud == XCD

    int lane = tid & 63, w = tid >> 6;
    int quad = lane >> 4, l16 = lane & 15;
    int cb = w * 32;                                     // 8 waves x 32 cols = 256

    // ---- pinned B: k-slices 0..3 (32 VGPRs)
    s8v bfrag[4][2];
    #pragma unroll
    for (int k0 = 0; k0 < 4; ++k0)
        #pragma unroll
        for (int ct = 0; ct < 2; ++ct)
            bfrag[k0][ct] = *(const s8v*)(W2T + (cb + ct * 16 + l16) * 256 + k0 * 32 + quad * 8);

    // ---- prologue: w1c + meta for ALL 8 centers (exactly one (center,t) per thread)
    for (int i = tid; i < 768; i += 512) w1c_lds[i] = W1[65536 + i];
    {
        int pr = tid >> 6, t = tid & 63;
        int mm = m0 + pr, cc = mm * 4;
        int j = nbrg[mm * KNB + t];
        nbr_lds[pr][t] = (u16)j;
        float rx = pos[j * 3 + 0] - pos[cc * 3 + 0];
        float ry = pos[j * 3 + 1] - pos[cc * 3 + 1];
        float rz = pos[j * 3 + 2] - pos[cc * 3 + 2];
        const float* lf = lframes + cc * 9;
        f4v r;
        r[0] = lf[0] * rx + lf[1] * ry + lf[2] * rz;
        r[1] = lf[3] * rx + lf[4] * ry + lf[5] * rz;
        r[2] = lf[6] * rx + lf[7] * ry + lf[8] * rz;
        r[3] = 0.0f;
        relc_lds[pr][t] = r;
    }
    if (tid >= 256 && tid < 384) {                       // aux outputs, all 8 centers
        int g = (tid - 256) >> 4, t = tid & 15;
        int mm = m0 + g, cc = mm * 4;
        if (t < 3)            out_pos[mm * 3 + t] = pos[cc * 3 + t];
        else if (t == 3)      out_batch[mm] = (float)batch[cc];
        else if (t < 13)      out_lf[mm * 9 + (t - 4)] = lframes[cc * 9 + (t - 4)];
    }

    int co = (tid & 31) * 8;
    int rs = tid >> 5;                                   // 0..15
    __syncthreads();                                     // meta + w1c ready

    for (int p = 0; p < 8; ++p) {
        int cvp = cnt[m0 + p];                           // uniform, L2-hot
        // ---- phase 1: h[64][256] = relu(u[nbr] + v + relc @ W1c)
        {
            const float* vp = v + (m0 + p) * 256 + co;
            f4v vq0 = *(const f4v*)vp;
            f4v vq1 = *(const f4v*)(vp + 4);
            f4v wa0 = *(const f4v*)&w1c_lds[co],       wa1 = *(const f4v*)&w1c_lds[co + 4];
            f4v wb0 = *(const f4v*)&w1c_lds[256 + co], wb1 = *(const f4v*)&w1c_lds[256 + co + 4];
            f4v wc0 = *(const f4v*)&w1c_lds[512 + co], wc1 = *(const f4v*)&w1c_lds[512 + co + 4];
            u4v uu[4];
            f4v rr[4];
            #pragma unroll
            for (int i2 = 0; i2 < 4; ++i2) {             // issue all 4 gathers first
                int rl = rs + i2 * 16;
                int j = (int)nbr_lds[p][rl];
                uu[i2] = *(const u4v*)(u + j * 256 + co);
                rr[i2] = relc_lds[p][rl];
            }
            #pragma unroll
            for (int i2 = 0; i2 < 4; ++i2) {
                int rl = rs + i2 * 16;
                f4v r = rr[i2];
                float p8[8];
                #pragma unroll
                for (int e = 0; e < 8; ++e) {
                    u32 bits = (e & 1) ? (uu[i2][e >> 1] & 0xFFFF0000u) : (uu[i2][e >> 1] << 16);
                    float va = (e < 4) ? vq0[e] : vq1[e - 4];
                    float a0 = (e < 4) ? wa0[e] : wa1[e - 4];
                    float b0 = (e < 4) ? wb0[e] : wb1[e - 4];
                    float c0 = (e < 4) ? wc0[e] : wc1[e - 4];
                    float pre = fmaf(r[0], a0, fmaf(r[1], b0, fmaf(r[2], c0,
                                  va + __uint_as_float(bits))));
                    p8[e] = fmaxf(pre, 0.0f);
                }
                u4v pk;
                #pragma unroll
                for (int d = 0; d < 4; ++d)
                    pk[d] = __builtin_amdgcn_perm(__float_as_uint(p8[2 * d + 1]),
                                                  __float_as_uint(p8[2 * d]), 0x07060302u);
                *(u4v*)&h_lds[rl * 264 + co] = pk;
            }
        }
        __syncthreads();                                 // h ready

        // ---- phase 2: [64x256] @ [256x256(cols 32/wave)]; B: 4 pinned + 4 streamed
        s8v bs[4][2];
        #pragma unroll
        for (int kk = 0; kk < 4; ++kk)                   // issue streams early, MFMA covers
            #pragma unroll
            for (int ct = 0; ct < 2; ++ct)
                bs[kk][ct] = *(const s8v*)(W2T + (cb + ct * 16 + l16) * 256 + (4 + kk) * 32 + quad * 8);
        f4v acc[4][2] = {};
        #pragma unroll
        for (int k0 = 0; k0 < 4; ++k0) {
            s8v a[4];
            #pragma unroll
            for (int rt = 0; rt < 4; ++rt)
                a[rt] = *(const s8v*)&h_lds[(rt * 16 + l16) * 264 + k0 * 32 + quad * 8];
            #pragma unroll
            for (int rt = 0; rt < 4; ++rt)
                #pragma unroll
                for (int ct = 0; ct < 2; ++ct)
                    acc[rt][ct] = __builtin_amdgcn_mfma_f32_16x16x32_bf16(a[rt], bfrag[k0][ct], acc[rt][ct], 0, 0, 0);
        }
        #pragma unroll
        for (int kk = 0; kk < 4; ++kk) {
            int k0 = 4 + kk;
            s8v a[4];
            #pragma unroll
            for (int rt = 0; rt < 4; ++rt)
                a[rt] = *(const s8v*)&h_lds[(rt * 16 + l16) * 264 + k0 * 32 + quad * 8];
            #pragma unroll
            for (int rt = 0; rt < 4; ++rt)
                #pragma unroll
                for (int ct = 0; ct < 2; ++ct)
                    acc[rt][ct] = __builtin_amdgcn_mfma_f32_16x16x32_bf16(a[rt], bs[kk][ct], acc[rt][ct], 0, 0, 0);
        }
        // ---- epilogue: masked max over rows, + b2
        int mout = m0 + p;
        #pragma unroll
        for (int ct = 0; ct < 2; ++ct) {
            float mx = -__builtin_inff();
            #pragma unroll
            for (int rt = 0; rt < 4; ++rt)
                #pragma unroll
                for (int g = 0; g < 4; ++g) {
                    int row = rt * 16 + quad * 4 + g;
                    float val = acc[rt][ct][g];
                    if (row < cvp) mx = fmaxf(mx, val);
                }
            mx = fmaxf(mx, __shfl_xor(mx, 16, 64));
            mx = fmaxf(mx, __shfl_xor(mx, 32, 64));
            if (lane < 16)
                out0[mout * 256 + cb + ct * 16 + l16] = mx + b2[cb + ct * 16 + l16];
        }
        if (p < 7) __syncthreads();                      // protect h before next overwrite
    }
}

extern "C" void kernel_launch(void* const* d_in, const int* in_sizes, int n_in,
                              void* d_out, int out_size, void* d_ws, size_t ws_size,
                              hipStream_t stream) {
    const float* x       = (const float*)d_in[0];
    const float* pos     = (const float*)d_in[1];
    const int*   batch   = (const int*)d_in[2];
    const float* lframes = (const float*)d_in[3];
    const float* W1      = (const float*)d_in[4];
    const float* b1      = (const float*)d_in[5];
    const float* W2      = (const float*)d_in[6];
    const float* b2      = (const float*)d_in[7];

    float* out       = (float*)d_out;
    float* out_pos   = out + M_CTR * 256;
    float* out_batch = out_pos + M_CTR * 3;
    float* out_lf    = out_batch + M_CTR;

    char* ws = (char*)d_ws;
    u16*   u_ws = (u16*)(ws);                    // N*256 bf16   = 8 MB
    float* v_ws = (float*)(ws + 8388608);        // M*256 f32    = 4 MB
    u16*   W1aT = (u16*)(ws + 12582912);
    u16*   W1bT = (u16*)(ws + 12648448);
    u16*   W2T  = (u16*)(ws + 12713984);
    int*   nbr  = (int*)(ws + 12845056);
    int*   cntp = (int*)(ws + 13893632);

    hipLaunchKernelGGL(ballq_kernel, dim3(M_CTR), dim3(256), 0, stream,
                       pos, nbr, cntp, W1, W2, W1aT, W1bT, W2T);
    hipLaunchKernelGGL(gemm_xw_kernel, dim3(320), dim3(256), 0, stream,
                       x, W1aT, W1bT, b1, u_ws, v_ws);
    hipLaunchKernelGGL(edge_kernel, dim3(512), dim3(512), 0, stream,
                       u_ws, v_ws, W2T, W1, b2, pos, lframes, batch, nbr, cntp,
                       out, out_pos, out_batch, out_lf);
}

// Round 11
// 162.402 us; speedup vs baseline: 1.1734x; 1.0630x over previous
//
#include <hip/hip_runtime.h>
#include <hip/hip_bf16.h>

#define N_PTS 16384
#define PER   2048
#define M_CTR 4096
#define KNB   64
#define C_IN  128
#define HID   256
#define C_OUT 256

typedef unsigned short u16;
typedef unsigned int u32;
typedef __attribute__((ext_vector_type(8))) short s8v;    // 8 bf16 (4 VGPRs)
typedef __attribute__((ext_vector_type(4))) float f4v;
typedef __attribute__((ext_vector_type(4))) unsigned int u4v;

static __device__ __forceinline__ u16 f2bf(float f) {
    union { float f; unsigned int i; } v; v.f = f;
    unsigned int r = v.i + 0x7FFFu + ((v.i >> 16) & 1u);
    return (u16)(r >> 16);
}

// ---------------------------------------------------------------- ballq (+prep folded into first 256 blocks)
// r10: byte-exact restore of the r3-best (162.0us) version. Session evidence:
// both ballq restructures regressed (wave-per-center +28us, segmented +10.6us);
// the atomic-compaction form is empirically fastest. Models that "explained" its
// cost were falsified twice — do not touch without per-kernel counters.
__global__ __launch_bounds__(256) void ballq_kernel(
        const float* __restrict__ pos, int* __restrict__ nbr, int* __restrict__ cnt,
        const float* __restrict__ W1, const float* __restrict__ W2,
        u16* __restrict__ W1aT, u16* __restrict__ W1bT, u16* __restrict__ W2T) {
    __shared__ float cd2[1024];
    __shared__ int   cidx[1024];
    __shared__ int   s_n;
    int m = blockIdx.x, tid = threadIdx.x;

    if (m < 256) {
        int gid = m * 256 + tid;
        int cc = gid >> 8, k = gid & 255;
        W2T[gid] = f2bf(W2[k * 256 + cc]);               // W2T[c][k]
        if (gid < 32768) {
            int c1 = gid >> 7, k1 = gid & 127;
            W1aT[gid] = f2bf(W1[k1 * 256 + c1]);         // rows 0:128
            W1bT[gid] = f2bf(W1[(k1 + 128) * 256 + c1]); // rows 128:256
        }
    }

    int c = m * 4;
    int base = (m >> 9) << 11;                            // cloud start
    int ln = tid & 63;
    if (tid == 0) s_n = 0;
    __syncthreads();
    float cx = pos[c * 3 + 0], cy = pos[c * 3 + 1], cz = pos[c * 3 + 2];
    float A = __fadd_rn(__fadd_rn(__fmul_rn(cx, cx), __fmul_rn(cy, cy)), __fmul_rn(cz, cz));
    float c2x = __fmul_rn(2.0f, cx);
    float c2y = __fmul_rn(2.0f, cy);
    float c2z = __fmul_rn(2.0f, cz);
    for (int s = 0; s < 8; ++s) {
        int j = base + tid + (s << 8);
        float px = pos[j * 3 + 0], py = pos[j * 3 + 1], pz = pos[j * 3 + 2];
        float B = __fadd_rn(__fadd_rn(__fmul_rn(px, px), __fmul_rn(py, py)), __fmul_rn(pz, pz));
        float C = __fmaf_rn(c2z, pz, __fmaf_rn(c2y, py, __fmul_rn(c2x, px)));
        float d2 = __fsub_rn(__fadd_rn(A, B), C);
        bool hit = (d2 <= 0.0625f);
        unsigned long long mk = __ballot(hit);
        int nb = __popcll(mk & ((1ull << ln) - 1ull));
        int tot = __popcll(mk);
        int bidx = 0;
        if (ln == 0 && tot) bidx = atomicAdd(&s_n, tot);
        bidx = __shfl(bidx, 0, 64);
        if (hit) {
            int a = bidx + nb;
            if (a < 1024) { cd2[a] = d2; cidx[a] = j; }
        }
    }
    __syncthreads();
    int V = s_n < 1024 ? s_n : 1024;
    if (V <= KNB) {
        if (tid < KNB) nbr[m * KNB + tid] = (tid < V) ? cidx[tid] : c;
        if (tid == 0) cnt[m] = V;
    } else {
        for (int e = tid; e < V; e += 256) {
            float de = cd2[e]; int ie = cidx[e];
            int rank = 0;
            for (int q = 0; q < V; ++q) {
                float dq = cd2[q];
                rank += (dq < de) || (dq == de && cidx[q] < ie);
            }
            if (rank < KNB) nbr[m * KNB + rank] = cidx[e];
        }
        if (tid == 0) cnt[m] = KNB;
    }
}

// ---------------------------------------------------------------- fused u = x@W1a (blocks 0..255) / v = x[4m]@W1b + b1 (blocks 256..319)
// r8 lesson: building B straight from W1 = stride-1KB scalar loads, +~25us. Keep
// the pre-transposed W1aT/W1bT intermediate (contiguous s8v fragments).
__global__ __launch_bounds__(256) void gemm_xw_kernel(
        const float* __restrict__ x, const u16* __restrict__ W1aT, const u16* __restrict__ W1bT,
        const float* __restrict__ b1, u16* __restrict__ u_out, float* __restrict__ v_out) {
    __shared__ u16 x_lds[64 * 136];
    int blk = blockIdx.x, tid = threadIdx.x;
    int mode = blk >= 256 ? 1 : 0;
    int bb = mode ? blk - 256 : blk;
    const u16* WT = mode ? W1bT : W1aT;
    {
        int r = tid >> 2, q = tid & 3;
        int xrow = bb * 64 + r;
        if (mode) xrow *= 4;
        const float* xp = x + xrow * C_IN + q * 32;
        u16* dst = x_lds + r * 136 + q * 32;
        for (int i = 0; i < 8; ++i) {
            f4v f = *(const f4v*)(xp + i * 4);
            dst[i * 4 + 0] = f2bf(f[0]);
            dst[i * 4 + 1] = f2bf(f[1]);
            dst[i * 4 + 2] = f2bf(f[2]);
            dst[i * 4 + 3] = f2bf(f[3]);
        }
    }
    __syncthreads();
    int lane = tid & 63, w = tid >> 6;
    int quad = lane >> 4, l16 = lane & 15;
    int cb = w * 64;
    f4v acc[4][4] = {};
    for (int k0 = 0; k0 < 128; k0 += 32) {
        s8v a[4], b[4];
        for (int rt = 0; rt < 4; ++rt)
            a[rt] = *(const s8v*)&x_lds[(rt * 16 + l16) * 136 + k0 + quad * 8];
        for (int ct = 0; ct < 4; ++ct)
            b[ct] = *(const s8v*)(WT + (cb + ct * 16 + l16) * 128 + k0 + quad * 8);
        for (int rt = 0; rt < 4; ++rt)
            for (int ct = 0; ct < 4; ++ct)
                acc[rt][ct] = __builtin_amdgcn_mfma_f32_16x16x32_bf16(a[rt], b[ct], acc[rt][ct], 0, 0, 0);
    }
    for (int rt = 0; rt < 4; ++rt)
        for (int ct = 0; ct < 4; ++ct)
            for (int g = 0; g < 4; ++g) {
                int row = rt * 16 + quad * 4 + g;
                int col = cb + ct * 16 + l16;
                float val = acc[rt][ct][g];
                int orow = bb * 64 + row;
                if (mode == 0) u_out[orow * 256 + col] = f2bf(val);
                else           v_out[orow * 256 + col] = val + b1[col];
            }
}

// ---------------------------------------------------------------- fused edge conv
// BYTE-EXACT r2 structure (proven 57.8-58.7us across r3/r8/r10: 8 centers/block,
// grid 512, w1c in LDS, bs loaded AFTER the barrier, NO setprio).
// HARD RULES (6x confirmed): allocator pins 64 VGPRs here; any extra live state
// (cross-barrier or intra-phase-1) spills -> FETCH/WRITE explode by 30-90 MB;
// even s_setprio perturbs scheduling into spill. Fixed point: DO NOT TOUCH.
__global__ __launch_bounds__(512, 4) void edge_kernel(
        const u16* __restrict__ u, const float* __restrict__ v,
        const u16* __restrict__ W2T, const float* __restrict__ W1,
        const float* __restrict__ b2, const float* __restrict__ pos,
        const float* __restrict__ lframes, const int* __restrict__ batch,
        const int* __restrict__ nbrg, const int* __restrict__ cnt,
        float* __restrict__ out0, float* __restrict__ out_pos,
        float* __restrict__ out_batch, float* __restrict__ out_lf) {
    __shared__ u16   h_lds[64 * 264];                    // 33792 B
    __shared__ float w1c_lds[768];                       // 3072 B
    __shared__ f4v   relc_lds[8][64];                    // 8192 B
    __shared__ u16   nbr_lds[8][64];                     // 1024 B
    // total 46080 B; occupancy grid-capped at 2 blocks/CU

    int blk = blockIdx.x, tid = threadIdx.x;
    int m0 = ((blk & 7) << 9) | ((blk >> 3) << 3);       // 8 consecutive centers, cloud == XCD

    int lane = tid & 63, w = tid >> 6;
    int quad = lane >> 4, l16 = lane & 15;
    int cb = w * 32;                                     // 8 waves x 32 cols = 256

    // ---- pinned B: k-slices 0..3 (32 VGPRs)
    s8v bfrag[4][2];
    #pragma unroll
    for (int k0 = 0; k0 < 4; ++k0)
        #pragma unroll
        for (int ct = 0; ct < 2; ++ct)
            bfrag[k0][ct] = *(const s8v*)(W2T + (cb + ct * 16 + l16) * 256 + k0 * 32 + quad * 8);

    // ---- prologue: w1c + meta for ALL 8 centers (exactly one (center,t) per thread)
    for (int i = tid; i < 768; i += 512) w1c_lds[i] = W1[65536 + i];
    {
        int pr = tid >> 6, t = tid & 63;
        int mm = m0 + pr, cc = mm * 4;
        int j = nbrg[mm * KNB + t];
        nbr_lds[pr][t] = (u16)j;
        float rx = pos[j * 3 + 0] - pos[cc * 3 + 0];
        float ry = pos[j * 3 + 1] - pos[cc * 3 + 1];
        float rz = pos[j * 3 + 2] - pos[cc * 3 + 2];
        const float* lf = lframes + cc * 9;
        f4v r;
        r[0] = lf[0] * rx + lf[1] * ry + lf[2] * rz;
        r[1] = lf[3] * rx + lf[4] * ry + lf[5] * rz;
        r[2] = lf[6] * rx + lf[7] * ry + lf[8] * rz;
        r[3] = 0.0f;
        relc_lds[pr][t] = r;
    }
    if (tid >= 256 && tid < 384) {                       // aux outputs, all 8 centers
        int g = (tid - 256) >> 4, t = tid & 15;
        int mm = m0 + g, cc = mm * 4;
        if (t < 3)            out_pos[mm * 3 + t] = pos[cc * 3 + t];
        else if (t == 3)      out_batch[mm] = (float)batch[cc];
        else if (t < 13)      out_lf[mm * 9 + (t - 4)] = lframes[cc * 9 + (t - 4)];
    }

    int co = (tid & 31) * 8;
    int rs = tid >> 5;                                   // 0..15
    __syncthreads();                                     // meta + w1c ready

    for (int p = 0; p < 8; ++p) {
        int cvp = cnt[m0 + p];                           // uniform, L2-hot
        // ---- phase 1: h[64][256] = relu(u[nbr] + v + relc @ W1c)
        {
            const float* vp = v + (m0 + p) * 256 + co;
            f4v vq0 = *(const f4v*)vp;
            f4v vq1 = *(const f4v*)(vp + 4);
            f4v wa0 = *(const f4v*)&w1c_lds[co],       wa1 = *(const f4v*)&w1c_lds[co + 4];
            f4v wb0 = *(const f4v*)&w1c_lds[256 + co], wb1 = *(const f4v*)&w1c_lds[256 + co + 4];
            f4v wc0 = *(const f4v*)&w1c_lds[512 + co], wc1 = *(const f4v*)&w1c_lds[512 + co + 4];
            u4v uu[4];
            f4v rr[4];
            #pragma unroll
            for (int i2 = 0; i2 < 4; ++i2) {             // issue all 4 gathers first
                int rl = rs + i2 * 16;
                int j = (int)nbr_lds[p][rl];
                uu[i2] = *(const u4v*)(u + j * 256 + co);
                rr[i2] = relc_lds[p][rl];
            }
            #pragma unroll
            for (int i2 = 0; i2 < 4; ++i2) {
                int rl = rs + i2 * 16;
                f4v r = rr[i2];
                float p8[8];
                #pragma unroll
                for (int e = 0; e < 8; ++e) {
                    u32 bits = (e & 1) ? (uu[i2][e >> 1] & 0xFFFF0000u) : (uu[i2][e >> 1] << 16);
                    float va = (e < 4) ? vq0[e] : vq1[e - 4];
                    float a0 = (e < 4) ? wa0[e] : wa1[e - 4];
                    float b0 = (e < 4) ? wb0[e] : wb1[e - 4];
                    float c0 = (e < 4) ? wc0[e] : wc1[e - 4];
                    float pre = fmaf(r[0], a0, fmaf(r[1], b0, fmaf(r[2], c0,
                                  va + __uint_as_float(bits))));
                    p8[e] = fmaxf(pre, 0.0f);
                }
                u4v pk;
                #pragma unroll
                for (int d = 0; d < 4; ++d)
                    pk[d] = __builtin_amdgcn_perm(__float_as_uint(p8[2 * d + 1]),
                                                  __float_as_uint(p8[2 * d]), 0x07060302u);
                *(u4v*)&h_lds[rl * 264 + co] = pk;
            }
        }
        __syncthreads();                                 // h ready

        // ---- phase 2: [64x256] @ [256x256(cols 32/wave)]; B: 4 pinned + 4 streamed
        s8v bs[4][2];
        #pragma unroll
        for (int kk = 0; kk < 4; ++kk)                   // issue streams early, MFMA covers
            #pragma unroll
            for (int ct = 0; ct < 2; ++ct)
                bs[kk][ct] = *(const s8v*)(W2T + (cb + ct * 16 + l16) * 256 + (4 + kk) * 32 + quad * 8);
        f4v acc[4][2] = {};
        #pragma unroll
        for (int k0 = 0; k0 < 4; ++k0) {
            s8v a[4];
            #pragma unroll
            for (int rt = 0; rt < 4; ++rt)
                a[rt] = *(const s8v*)&h_lds[(rt * 16 + l16) * 264 + k0 * 32 + quad * 8];
            #pragma unroll
            for (int rt = 0; rt < 4; ++rt)
                #pragma unroll
                for (int ct = 0; ct < 2; ++ct)
                    acc[rt][ct] = __builtin_amdgcn_mfma_f32_16x16x32_bf16(a[rt], bfrag[k0][ct], acc[rt][ct], 0, 0, 0);
        }
        #pragma unroll
        for (int kk = 0; kk < 4; ++kk) {
            int k0 = 4 + kk;
            s8v a[4];
            #pragma unroll
            for (int rt = 0; rt < 4; ++rt)
                a[rt] = *(const s8v*)&h_lds[(rt * 16 + l16) * 264 + k0 * 32 + quad * 8];
            #pragma unroll
            for (int rt = 0; rt < 4; ++rt)
                #pragma unroll
                for (int ct = 0; ct < 2; ++ct)
                    acc[rt][ct] = __builtin_amdgcn_mfma_f32_16x16x32_bf16(a[rt], bs[kk][ct], acc[rt][ct], 0, 0, 0);
        }
        // ---- epilogue: masked max over rows, + b2
        int mout = m0 + p;
        #pragma unroll
        for (int ct = 0; ct < 2; ++ct) {
            float mx = -__builtin_inff();
            #pragma unroll
            for (int rt = 0; rt < 4; ++rt)
                #pragma unroll
                for (int g = 0; g < 4; ++g) {
                    int row = rt * 16 + quad * 4 + g;
                    float val = acc[rt][ct][g];
                    if (row < cvp) mx = fmaxf(mx, val);
                }
            mx = fmaxf(mx, __shfl_xor(mx, 16, 64));
            mx = fmaxf(mx, __shfl_xor(mx, 32, 64));
            if (lane < 16)
                out0[mout * 256 + cb + ct * 16 + l16] = mx + b2[cb + ct * 16 + l16];
        }
        if (p < 7) __syncthreads();                      // protect h before next overwrite
    }
}

extern "C" void kernel_launch(void* const* d_in, const int* in_sizes, int n_in,
                              void* d_out, int out_size, void* d_ws, size_t ws_size,
                              hipStream_t stream) {
    const float* x       = (const float*)d_in[0];
    const float* pos     = (const float*)d_in[1];
    const int*   batch   = (const int*)d_in[2];
    const float* lframes = (const float*)d_in[3];
    const float* W1      = (const float*)d_in[4];
    const float* b1      = (const float*)d_in[5];
    const float* W2      = (const float*)d_in[6];
    const float* b2      = (const float*)d_in[7];

    float* out       = (float*)d_out;
    float* out_pos   = out + M_CTR * 256;
    float* out_batch = out_pos + M_CTR * 3;
    float* out_lf    = out_batch + M_CTR;

    char* ws = (char*)d_ws;
    u16*   u_ws = (u16*)(ws);                    // N*256 bf16   = 8 MB
    float* v_ws = (float*)(ws + 8388608);        // M*256 f32    = 4 MB
    u16*   W1aT = (u16*)(ws + 12582912);
    u16*   W1bT = (u16*)(ws + 12648448);
    u16*   W2T  = (u16*)(ws + 12713984);
    int*   nbr  = (int*)(ws + 12845056);
    int*   cntp = (int*)(ws + 13893632);

    hipLaunchKernelGGL(ballq_kernel, dim3(M_CTR), dim3(256), 0, stream,
                       pos, nbr, cntp, W1, W2, W1aT, W1bT, W2T);
    hipLaunchKernelGGL(gemm_xw_kernel, dim3(320), dim3(256), 0, stream,
                       x, W1aT, W1bT, b1, u_ws, v_ws);
    hipLaunchKernelGGL(edge_kernel, dim3(512), dim3(512), 0, stream,
                       u_ws, v_ws, W2T, W1, b2, pos, lframes, batch, nbr, cntp,
                       out, out_pos, out_batch, out_lf);
}